// Round 15
// baseline (401.082 us; speedup 1.0000x reference)
//
#include <hip/hip_runtime.h>
#include <hip/hip_bf16.h>
#include <math.h>

// Problem constants
#define BATCH 16384
#define DIN   480
#define DH    512
#define DOUT  360
#define NEXP  8
#define GIN   64
#define GH    128
#define KP    512          // padded K for all expert layers

typedef short bf16x8 __attribute__((ext_vector_type(8)));
typedef float f32x4  __attribute__((ext_vector_type(4)));

__device__ __forceinline__ short f2bf(float f) {
    __hip_bfloat16 h = __float2bfloat16(f);
    return *reinterpret_cast<short*>(&h);
}
__device__ __forceinline__ float eluf(float x) { return x > 0.f ? x : expf(x) - 1.f; }

__device__ __forceinline__ void gll16(const void* g, void* l) {
    __builtin_amdgcn_global_load_lds(
        (const __attribute__((address_space(1))) unsigned int*)g,
        (__attribute__((address_space(3))) unsigned int*)l, 16, 0, 0);
}

// ---------------------------------------------------------------------------
// Kernel 1: xn = (x - mu) / sigma -> bf16, pitch 512 (cols 480..511 zero).
// ---------------------------------------------------------------------------
__global__ void prep_xn_kernel(const float* __restrict__ x,
                               const float* __restrict__ Xnorm,
                               short* __restrict__ xnbf) {
    const int tid = blockIdx.x * 256 + threadIdx.x;
    const int row = tid >> 6;
    const int c   = (tid & 63) * 8;
    short v8[8];
    if (c < DIN) {
        #pragma unroll
        for (int j = 0; j < 8; ++j) {
            float v = (x[(size_t)row * DIN + c + j] - Xnorm[c + j]) / Xnorm[DIN + c + j];
            v8[j] = f2bf(v);
        }
    } else {
        #pragma unroll
        for (int j = 0; j < 8; ++j) v8[j] = 0;
    }
    *(uint4*)&xnbf[(size_t)row * KP + c] = *(uint4*)v8;
}

// ---------------------------------------------------------------------------
// Kernel 2: transpose + convert W (E,K,N) f32 -> Wt (E,NPAD,KP) bf16, zero pad.
// ---------------------------------------------------------------------------
__global__ void transpose_w_kernel(const float* __restrict__ src,
                                   short* __restrict__ dst,
                                   int K, int N, int NPAD) {
    __shared__ float tile[32][33];
    const int ntn = NPAD / 32;
    const int ntk = KP / 32;
    int lin = blockIdx.x;
    const int e  = lin / (ntk * ntn);
    lin -= e * ntk * ntn;
    const int kt = lin / ntn;
    const int nt = lin % ntn;
    const int t = threadIdx.x;
    #pragma unroll
    for (int r = 0; r < 4; ++r) {
        int idx = t + r * 256;
        int i = idx >> 5;          // k within tile
        int j = idx & 31;          // n within tile
        int k = kt * 32 + i;
        int n = nt * 32 + j;
        float v = (n < N && k < K) ? src[((size_t)e * K + k) * N + n] : 0.f;
        tile[i][j] = v;
    }
    __syncthreads();
    #pragma unroll
    for (int r = 0; r < 4; ++r) {
        int idx = t + r * 256;
        int i2 = idx & 31;         // k (contiguous on write)
        int j2 = idx >> 5;         // n
        dst[((size_t)e * NPAD + nt * 32 + j2) * KP + kt * 32 + i2] = f2bf(tile[i2][j2]);
    }
}

// ---------------------------------------------------------------------------
// Kernel 3: gating MLP -> softmax weights w[B][8] (fp32).
// ---------------------------------------------------------------------------
__global__ __launch_bounds__(256) void gating_kernel(
    const float* __restrict__ x, const float* __restrict__ Xnorm,
    const float* __restrict__ G1W, const float* __restrict__ G1b,
    const float* __restrict__ G2W, const float* __restrict__ G2b,
    const float* __restrict__ G3W, const float* __restrict__ G3b,
    const int* __restrict__ gidx, float* __restrict__ wout) {

    __shared__ float g2s[GH * GH];
    __shared__ float g3s[GH * NEXP];
    __shared__ float b1s[GH], b2s[GH], b3s[NEXP];
    __shared__ float g0b[4][GIN], h1b[4][GH], h2b[4][GH];

    const int t = threadIdx.x;
    const int lane = t & 63;
    const int wid  = t >> 6;

    for (int i = t; i < GH * GH; i += 256) g2s[i] = G2W[i];
    for (int i = t; i < GH * NEXP; i += 256) g3s[i] = G3W[i];
    if (t < GH) { b1s[t] = G1b[t]; b2s[t] = G2b[t]; }
    if (t < NEXP) b3s[t] = G3b[t];
    __syncthreads();

    const int gi = gidx[lane];
    const float mu = Xnorm[gi];
    const float inv_sig = 1.f / Xnorm[DIN + gi];

    for (int it = 0; it < 16; ++it) {
        const int row = (blockIdx.x * 4 + wid) * 16 + it;
        float g0 = (x[(size_t)row * DIN + gi] - mu) * inv_sig;
        g0b[wid][lane] = g0;
        __syncthreads();
        float h1a = b1s[lane], h1c = b1s[lane + 64];
        #pragma unroll 8
        for (int i = 0; i < GIN; ++i) {
            float g = g0b[wid][i];
            h1a += g * G1W[i * GH + lane];
            h1c += g * G1W[i * GH + lane + 64];
        }
        h1b[wid][lane] = eluf(h1a);
        h1b[wid][lane + 64] = eluf(h1c);
        __syncthreads();
        float h2a = b2s[lane], h2c = b2s[lane + 64];
        #pragma unroll 8
        for (int i = 0; i < GH; ++i) {
            float h = h1b[wid][i];
            h2a += h * g2s[i * GH + lane];
            h2c += h * g2s[i * GH + lane + 64];
        }
        h2b[wid][lane] = eluf(h2a);
        h2b[wid][lane + 64] = eluf(h2c);
        __syncthreads();
        const int e  = lane & 7;
        const int ch = lane >> 3;
        float p = 0.f;
        #pragma unroll
        for (int i2 = 0; i2 < 16; ++i2) {
            int i = ch * 16 + i2;
            p += h2b[wid][i] * g3s[i * NEXP + e];
        }
        p += __shfl_xor(p, 8);
        p += __shfl_xor(p, 16);
        p += __shfl_xor(p, 32);
        p += b3s[e];
        float mx = p;
        mx = fmaxf(mx, __shfl_xor(mx, 1));
        mx = fmaxf(mx, __shfl_xor(mx, 2));
        mx = fmaxf(mx, __shfl_xor(mx, 4));
        float ex = expf(p - mx);
        float sm = ex;
        sm += __shfl_xor(sm, 1);
        sm += __shfl_xor(sm, 2);
        sm += __shfl_xor(sm, 4);
        float wv = ex / sm;
        if (lane < NEXP) wout[(size_t)row * NEXP + lane] = wv;
        __syncthreads();
    }
}

// ---------------------------------------------------------------------------
// Kernel 4 v15: m97-faithful small-block MoE GEMM.
// BM=128, BN=64, BK=64; 256 threads = 4 waves (2M x 2N), wave tile 64x32,
// frags 4x2 -> acc+accF = 64 AGPR; target 3 waves/SIMD via
// __launch_bounds__(256,3) (168-reg wave). Single-buffered LDS (28 KB ->
// 3+ blocks/CU co-resident; independent blocks cover each other's barrier
// drains, the m97 mechanism). e-outer / kt-inner, acc accumulated in place
// over kt, mix accF += w_e*acc at expert boundary. Plain __syncthreads
// 2-barrier loop (compiler-managed waits). XOR slot-swizzle both sides.
// ---------------------------------------------------------------------------
template<int NPAD, int NREAL, int MODE>
__global__ __launch_bounds__(256, 3) void expert_v15_kernel(
    const short* __restrict__ A, const short* __restrict__ Wt,
    const float* __restrict__ wgate, const float* __restrict__ bias,
    const float* __restrict__ Ynorm, void* __restrict__ Out) {

    __shared__ __align__(16) short bufA[128 * 64];   // 16 KB
    __shared__ __align__(16) short bufB[64 * 64];    //  8 KB
    __shared__ float wlsT[NEXP][128];                //  4 KB

    const int t = threadIdx.x;
    const int lane = t & 63;
    const int wid  = t >> 6;          // 0..3
    const int wr = wid >> 1;          // 0..1 : 64-row strip
    const int wc = wid & 1;           // 0..1 : 32-col strip
    const int l4 = lane >> 4, lr = lane & 15;

    // XCD-chunked block swizzle (grid % 8 == 0 for all layers)
    constexpr int NN = NPAD / 64;
    constexpr int nwg = (BATCH / 128) * NN;
    constexpr int cpx = nwg / 8;
    const int lb  = (blockIdx.x & 7) * cpx + (blockIdx.x >> 3);
    const int m0  = (lb / NN) * 128;
    const int n0  = (lb % NN) * 64;

    // gating weights transposed: wlsT[e][row] = wgate[(m0+row)*8+e]
    for (int i = t; i < NEXP * 128; i += 256) {
        int e = i >> 7, r = i & 127;
        wlsT[e][r] = wgate[(size_t)(m0 + r) * NEXP + e];
    }

    // staging geometry: thread t handles chunk rows srow8 = t>>3 (0..31),
    // pre-swizzled slot sslot = (t&7) ^ (srow8 & 7).
    const int srow8 = t >> 3;
    const int sslot = (t & 7) ^ (srow8 & 7);

    // A: 4 chunks (rows i*32 + srow8), B: 2 chunks (rows srow8, 32+srow8)
    const short* srcA[4];
    #pragma unroll
    for (int i = 0; i < 4; ++i)
        srcA[i] = A + (size_t)(m0 + i * 32 + srow8) * KP + sslot * 8;
    const short* srcB0 = Wt + (size_t)(n0 + srow8) * KP + sslot * 8;
    const short* srcB1 = Wt + (size_t)(n0 + 32 + srow8) * KP + sslot * 8;

    f32x4 acc[4][2], accF[4][2];
    #pragma unroll
    for (int mi = 0; mi < 4; ++mi)
        #pragma unroll
        for (int ni = 0; ni < 2; ++ni)
            accF[mi][ni] = (f32x4){0.f, 0.f, 0.f, 0.f};

    const int xo0 = (l4 * 8) ^ ((lr & 7) << 3);
    const int xo1 = (32 + l4 * 8) ^ ((lr & 7) << 3);
    const int arow = (wr * 64 + lr) * 64;      // + mi*1024
    const int brow = (wc * 32 + lr) * 64;      // + ni*1024

    #pragma unroll 1
    for (int e = 0; e < NEXP; ++e) {
        #pragma unroll
        for (int mi = 0; mi < 4; ++mi)
            #pragma unroll
            for (int ni = 0; ni < 2; ++ni)
                acc[mi][ni] = (f32x4){0.f, 0.f, 0.f, 0.f};

        #pragma unroll 1
        for (int kt = 0; kt < 8; ++kt) {
            __syncthreads();   // all waves done reading previous step's tiles

            // stage A(kt) + B(e,kt): 6 x gll16 per thread
            const size_t ka = (size_t)kt * 64;
            const size_t kb = (size_t)e * NPAD * KP + ka;
            #pragma unroll
            for (int i = 0; i < 4; ++i)
                gll16(srcA[i] + ka, &bufA[(i * 256 + t) * 8]);
            gll16(srcB0 + kb, &bufB[t * 8]);
            gll16(srcB1 + kb, &bufB[(256 + t) * 8]);

            __syncthreads();   // implicit vmcnt(0) drain -> tiles published

            // compute: 2 kk-phases, 8 MFMA each
            {
                bf16x8 a[4], b[2];
                #pragma unroll
                for (int mi = 0; mi < 4; ++mi)
                    a[mi] = *(const bf16x8*)(&bufA[arow + mi * 1024 + xo0]);
                #pragma unroll
                for (int ni = 0; ni < 2; ++ni)
                    b[ni] = *(const bf16x8*)(&bufB[brow + ni * 1024 + xo0]);
                __builtin_amdgcn_s_setprio(1);
                #pragma unroll
                for (int mi = 0; mi < 4; ++mi)
                    #pragma unroll
                    for (int ni = 0; ni < 2; ++ni)
                        acc[mi][ni] = __builtin_amdgcn_mfma_f32_16x16x32_bf16(
                            a[mi], b[ni], acc[mi][ni], 0, 0, 0);
                __builtin_amdgcn_s_setprio(0);
            }
            {
                bf16x8 a[4], b[2];
                #pragma unroll
                for (int mi = 0; mi < 4; ++mi)
                    a[mi] = *(const bf16x8*)(&bufA[arow + mi * 1024 + xo1]);
                #pragma unroll
                for (int ni = 0; ni < 2; ++ni)
                    b[ni] = *(const bf16x8*)(&bufB[brow + ni * 1024 + xo1]);
                __builtin_amdgcn_s_setprio(1);
                #pragma unroll
                for (int mi = 0; mi < 4; ++mi)
                    #pragma unroll
                    for (int ni = 0; ni < 2; ++ni)
                        acc[mi][ni] = __builtin_amdgcn_mfma_f32_16x16x32_bf16(
                            a[mi], b[ni], acc[mi][ni], 0, 0, 0);
                __builtin_amdgcn_s_setprio(0);
            }
        }

        // expert boundary: accF += w_e[row] * acc
        #pragma unroll
        for (int mi = 0; mi < 4; ++mi) {
            f32x4 wv = *(const f32x4*)&wlsT[e][wr * 64 + mi * 16 + l4 * 4];
            #pragma unroll
            for (int ni = 0; ni < 2; ++ni)
                #pragma unroll
                for (int j = 0; j < 4; ++j)
                    accF[mi][ni][j] += wv[j] * acc[mi][ni][j];
        }
    }

    // epilogue: rank-1 bias term  accF += sum_e w_e[row] * bias_e[col]
    {
        float bv[2][NEXP];
        #pragma unroll
        for (int ni = 0; ni < 2; ++ni) {
            int ng = n0 + wc * 32 + ni * 16 + lr;
            #pragma unroll
            for (int e = 0; e < NEXP; ++e)
                bv[ni][e] = (ng < NREAL) ? bias[(size_t)e * NREAL + ng] : 0.f;
        }
        #pragma unroll
        for (int mi = 0; mi < 4; ++mi) {
            f32x4 wve[NEXP];
            #pragma unroll
            for (int e = 0; e < NEXP; ++e)
                wve[e] = *(const f32x4*)&wlsT[e][wr * 64 + mi * 16 + l4 * 4];
            #pragma unroll
            for (int ni = 0; ni < 2; ++ni)
                #pragma unroll
                for (int j = 0; j < 4; ++j) {
                    float sum = 0.f;
                    #pragma unroll
                    for (int e = 0; e < NEXP; ++e) sum += wve[e][j] * bv[ni][e];
                    accF[mi][ni][j] += sum;
                }
        }
    }

    // store
    #pragma unroll
    for (int mi = 0; mi < 4; ++mi) {
        #pragma unroll
        for (int j = 0; j < 4; ++j) {
            size_t rg = (size_t)(m0 + wr * 64 + mi * 16 + l4 * 4 + j);
            #pragma unroll
            for (int ni = 0; ni < 2; ++ni) {
                int ng = n0 + wc * 32 + ni * 16 + lr;
                float v = accF[mi][ni][j];
                if (MODE == 0) {
                    v = v > 0.f ? v : expf(v) - 1.f;
                    ((short*)Out)[rg * NPAD + ng] = f2bf(v);
                } else {
                    if (ng < NREAL)
                        ((float*)Out)[rg * NREAL + ng] = v * Ynorm[NREAL + ng] + Ynorm[ng];
                }
            }
        }
    }
}

// ---------------------------------------------------------------------------
extern "C" void kernel_launch(void* const* d_in, const int* in_sizes, int n_in,
                              void* d_out, int out_size, void* d_ws, size_t ws_size,
                              hipStream_t stream) {
    const float* x     = (const float*)d_in[0];
    const float* Xnorm = (const float*)d_in[1];
    const float* Ynorm = (const float*)d_in[2];
    const float* G1W   = (const float*)d_in[3];
    const float* G1b   = (const float*)d_in[4];
    const float* G2W   = (const float*)d_in[5];
    const float* G2b   = (const float*)d_in[6];
    const float* G3W   = (const float*)d_in[7];
    const float* G3b   = (const float*)d_in[8];
    const float* W1    = (const float*)d_in[9];
    const float* b1    = (const float*)d_in[10];
    const float* W2    = (const float*)d_in[11];
    const float* b2    = (const float*)d_in[12];
    const float* W3    = (const float*)d_in[13];
    const float* b3    = (const float*)d_in[14];
    const int*   gidx  = (const int*)d_in[15];

    // workspace layout (m2 aliases xnbf: xnbf is fully consumed by layer 1)
    char* ws = (char*)d_ws;
    size_t off = 0;
    short* xnbf = (short*)(ws + off); off += (size_t)BATCH * KP * 2;        // 16.8 MB
    short* m1   = (short*)(ws + off); off += (size_t)BATCH * DH * 2;        // 16.8 MB
    short* Wt1  = (short*)(ws + off); off += (size_t)NEXP * DH  * KP * 2;   // 4.2 MB
    short* Wt2  = (short*)(ws + off); off += (size_t)NEXP * DH  * KP * 2;   // 4.2 MB
    short* Wt3  = (short*)(ws + off); off += (size_t)NEXP * 384 * KP * 2;   // 3.1 MB
    float* wg   = (float*)(ws + off); off += (size_t)BATCH * NEXP * 4;      // 0.5 MB
    short* m2   = xnbf;
    if (off > ws_size) return;

    // 1. normalize x -> bf16 (pitch 512, zero-padded)
    prep_xn_kernel<<<BATCH * 64 / 256, 256, 0, stream>>>(x, Xnorm, xnbf);

    // 2. transpose weights to [E][NPAD][KP] bf16 (K zero-padded)
    transpose_w_kernel<<<NEXP * (KP / 32) * (DH / 32), 256, 0, stream>>>(W1, Wt1, DIN, DH, DH);
    transpose_w_kernel<<<NEXP * (KP / 32) * (DH / 32), 256, 0, stream>>>(W2, Wt2, DH, DH, DH);
    transpose_w_kernel<<<NEXP * (KP / 32) * (384 / 32), 256, 0, stream>>>(W3, Wt3, DH, DOUT, 384);

    // 3. gating -> w[B][8]
    gating_kernel<<<256, 256, 0, stream>>>(x, Xnorm, G1W, G1b, G2W, G2b, G3W, G3b, gidx, wg);

    // 4. expert layers (BM=128, BN=64)
    expert_v15_kernel<DH, DH, 0>
        <<<(BATCH / 128) * (DH / 64), 256, 0, stream>>>(xnbf, Wt1, wg, b1, Ynorm, m1);
    expert_v15_kernel<DH, DH, 0>
        <<<(BATCH / 128) * (DH / 64), 256, 0, stream>>>(m1, Wt2, wg, b2, Ynorm, m2);
    expert_v15_kernel<384, DOUT, 1>
        <<<(BATCH / 128) * (384 / 64), 256, 0, stream>>>(m2, Wt3, wg, b3, Ynorm, (void*)d_out);
}

// Round 16
// 322.530 us; speedup vs baseline: 1.2435x; 1.2435x over previous
//
#include <hip/hip_runtime.h>
#include <hip/hip_bf16.h>
#include <math.h>

// Problem constants
#define BATCH 16384
#define DIN   480
#define DH    512
#define DOUT  360
#define NEXP  8
#define GIN   64
#define GH    128
#define KP    512          // padded K for all expert layers

typedef short bf16x8 __attribute__((ext_vector_type(8)));
typedef float f32x4  __attribute__((ext_vector_type(4)));

__device__ __forceinline__ short f2bf(float f) {
    __hip_bfloat16 h = __float2bfloat16(f);
    return *reinterpret_cast<short*>(&h);
}
__device__ __forceinline__ float eluf(float x) { return x > 0.f ? x : expf(x) - 1.f; }

__device__ __forceinline__ void gll16(const void* g, void* l) {
    __builtin_amdgcn_global_load_lds(
        (const __attribute__((address_space(1))) unsigned int*)g,
        (__attribute__((address_space(3))) unsigned int*)l, 16, 0, 0);
}

// ---------------------------------------------------------------------------
// Kernel 1: xn = (x - mu) / sigma -> bf16, pitch 512 (cols 480..511 zero).
// ---------------------------------------------------------------------------
__global__ void prep_xn_kernel(const float* __restrict__ x,
                               const float* __restrict__ Xnorm,
                               short* __restrict__ xnbf) {
    const int tid = blockIdx.x * 256 + threadIdx.x;
    const int row = tid >> 6;
    const int c   = (tid & 63) * 8;
    short v8[8];
    if (c < DIN) {
        #pragma unroll
        for (int j = 0; j < 8; ++j) {
            float v = (x[(size_t)row * DIN + c + j] - Xnorm[c + j]) / Xnorm[DIN + c + j];
            v8[j] = f2bf(v);
        }
    } else {
        #pragma unroll
        for (int j = 0; j < 8; ++j) v8[j] = 0;
    }
    *(uint4*)&xnbf[(size_t)row * KP + c] = *(uint4*)v8;
}

// ---------------------------------------------------------------------------
// Kernel 2 (merged): transpose + convert all three W (E,K,N) f32 ->
// Wt (E,NPAD,KP) bf16, zero pad. One launch; block index selects tensor.
// W1: K=480,N=512,NPAD=512 (2048 blocks); W2: 512,512,512 (2048);
// W3: 512,360,NPAD=384 (1536). grid = 5632.
// ---------------------------------------------------------------------------
__global__ void transpose_all_kernel(const float* __restrict__ W1s, short* __restrict__ Wt1,
                                     const float* __restrict__ W2s, short* __restrict__ Wt2,
                                     const float* __restrict__ W3s, short* __restrict__ Wt3) {
    __shared__ float tile[32][33];
    int lin = blockIdx.x;
    const float* src;
    short* dst;
    int K, N, NPAD;
    if (lin < 2048)      { src = W1s; dst = Wt1; K = DIN; N = DH;   NPAD = DH;  }
    else if (lin < 4096) { src = W2s; dst = Wt2; K = DH;  N = DH;   NPAD = DH;  lin -= 2048; }
    else                 { src = W3s; dst = Wt3; K = DH;  N = DOUT; NPAD = 384; lin -= 4096; }

    const int ntn = NPAD / 32;
    const int ntk = KP / 32;
    const int e  = lin / (ntk * ntn);
    lin -= e * ntk * ntn;
    const int kt = lin / ntn;
    const int nt = lin % ntn;
    const int t = threadIdx.x;
    #pragma unroll
    for (int r = 0; r < 4; ++r) {
        int idx = t + r * 256;
        int i = idx >> 5;          // k within tile
        int j = idx & 31;          // n within tile
        int k = kt * 32 + i;
        int n = nt * 32 + j;
        float v = (n < N && k < K) ? src[((size_t)e * K + k) * N + n] : 0.f;
        tile[i][j] = v;
    }
    __syncthreads();
    #pragma unroll
    for (int r = 0; r < 4; ++r) {
        int idx = t + r * 256;
        int i2 = idx & 31;         // k (contiguous on write)
        int j2 = idx >> 5;         // n
        dst[((size_t)e * NPAD + nt * 32 + j2) * KP + kt * 32 + i2] = f2bf(tile[i2][j2]);
    }
}

// ---------------------------------------------------------------------------
// Kernel 3: gating MLP -> softmax weights w[B][8] (fp32).
// ---------------------------------------------------------------------------
__global__ __launch_bounds__(256) void gating_kernel(
    const float* __restrict__ x, const float* __restrict__ Xnorm,
    const float* __restrict__ G1W, const float* __restrict__ G1b,
    const float* __restrict__ G2W, const float* __restrict__ G2b,
    const float* __restrict__ G3W, const float* __restrict__ G3b,
    const int* __restrict__ gidx, float* __restrict__ wout) {

    __shared__ float g2s[GH * GH];
    __shared__ float g3s[GH * NEXP];
    __shared__ float b1s[GH], b2s[GH], b3s[NEXP];
    __shared__ float g0b[4][GIN], h1b[4][GH], h2b[4][GH];

    const int t = threadIdx.x;
    const int lane = t & 63;
    const int wid  = t >> 6;

    for (int i = t; i < GH * GH; i += 256) g2s[i] = G2W[i];
    for (int i = t; i < GH * NEXP; i += 256) g3s[i] = G3W[i];
    if (t < GH) { b1s[t] = G1b[t]; b2s[t] = G2b[t]; }
    if (t < NEXP) b3s[t] = G3b[t];
    __syncthreads();

    const int gi = gidx[lane];
    const float mu = Xnorm[gi];
    const float inv_sig = 1.f / Xnorm[DIN + gi];

    for (int it = 0; it < 16; ++it) {
        const int row = (blockIdx.x * 4 + wid) * 16 + it;
        float g0 = (x[(size_t)row * DIN + gi] - mu) * inv_sig;
        g0b[wid][lane] = g0;
        __syncthreads();
        float h1a = b1s[lane], h1c = b1s[lane + 64];
        #pragma unroll 8
        for (int i = 0; i < GIN; ++i) {
            float g = g0b[wid][i];
            h1a += g * G1W[i * GH + lane];
            h1c += g * G1W[i * GH + lane + 64];
        }
        h1b[wid][lane] = eluf(h1a);
        h1b[wid][lane + 64] = eluf(h1c);
        __syncthreads();
        float h2a = b2s[lane], h2c = b2s[lane + 64];
        #pragma unroll 8
        for (int i = 0; i < GH; ++i) {
            float h = h1b[wid][i];
            h2a += h * g2s[i * GH + lane];
            h2c += h * g2s[i * GH + lane + 64];
        }
        h2b[wid][lane] = eluf(h2a);
        h2b[wid][lane + 64] = eluf(h2c);
        __syncthreads();
        const int e  = lane & 7;
        const int ch = lane >> 3;
        float p = 0.f;
        #pragma unroll
        for (int i2 = 0; i2 < 16; ++i2) {
            int i = ch * 16 + i2;
            p += h2b[wid][i] * g3s[i * NEXP + e];
        }
        p += __shfl_xor(p, 8);
        p += __shfl_xor(p, 16);
        p += __shfl_xor(p, 32);
        p += b3s[e];
        float mx = p;
        mx = fmaxf(mx, __shfl_xor(mx, 1));
        mx = fmaxf(mx, __shfl_xor(mx, 2));
        mx = fmaxf(mx, __shfl_xor(mx, 4));
        float ex = expf(p - mx);
        float sm = ex;
        sm += __shfl_xor(sm, 1);
        sm += __shfl_xor(sm, 2);
        sm += __shfl_xor(sm, 4);
        float wv = ex / sm;
        if (lane < NEXP) wout[(size_t)row * NEXP + lane] = wv;
        __syncthreads();
    }
}

// ---------------------------------------------------------------------------
// Kernel 4 v8 (best measured): kt-outer / e-inner, ROLLED loops,
// A-fragments hoisted to registers once per kt (bufA invariant for 8 e-steps)
// -> per-step LDS reads halve (B frags only). FIFO-audited vmcnt schedule:
// e==6 -> vmcnt(6); e==7 -> vmcnt(2) (drains A before next kt-top af reads);
// kt==7&&e>=6 -> vmcnt(0); else vmcnt(2). One barrier/step.
// ---------------------------------------------------------------------------
template<int NPAD, int NREAL, int MODE>
__global__ __launch_bounds__(512, 2) void expert_v8_kernel(
    const short* __restrict__ A, const short* __restrict__ Wt,
    const float* __restrict__ wgate, const float* __restrict__ bias,
    const float* __restrict__ Ynorm, void* __restrict__ Out) {

    __shared__ __align__(16) short bufA[2][256 * 64];   // 64 KB
    __shared__ __align__(16) short bufB[3][128 * 64];   // 48 KB
    __shared__ float wlsT[NEXP][256];                   // 8 KB

    const int t = threadIdx.x;
    const int lane = t & 63;
    const int wid  = t >> 6;          // 0..7
    const int wr = wid >> 1;          // 0..3 : 64-row strip
    const int wc = wid & 1;           // 0..1 : 64-col strip
    const int l4 = lane >> 4, lr = lane & 15;

    // XCD-chunked block swizzle (grid % 8 == 0 for all layers)
    constexpr int NN = NPAD / 128;
    constexpr int nwg = (BATCH / 256) * NN;
    constexpr int cpx = nwg / 8;
    const int lb  = (blockIdx.x & 7) * cpx + (blockIdx.x >> 3);
    const int m0  = (lb / NN) * 256;
    const int n0  = (lb % NN) * 128;

    // gating weights transposed: wlsT[e][row] = wgate[(m0+row)*8+e]
    for (int i = t; i < NEXP * 256; i += 512) {
        int e = i >> 8, r = i & 255;
        wlsT[e][r] = wgate[(size_t)(m0 + r) * NEXP + e];
    }

    // staging geometry: 16B chunk per lane; 8-row x 8-slot groups, XOR swizzle
    const int srow  = lane >> 3;              // 0..7
    const int sslot = (lane & 7) ^ srow;      // pre-swizzled source 16B-slot

    const short* baseA[4];
    #pragma unroll
    for (int i = 0; i < 4; ++i)
        baseA[i] = A + (size_t)(m0 + (wid * 4 + i) * 8 + srow) * KP + sslot * 8;
    const short* baseB[2];
    #pragma unroll
    for (int i = 0; i < 2; ++i)
        baseB[i] = Wt + (size_t)(n0 + (wid * 2 + i) * 8 + srow) * KP + sslot * 8;

    short* const bufA0 = &bufA[0][0];
    short* const bufB0 = &bufB[0][0];

    f32x4 accF[4][4];
    #pragma unroll
    for (int mi = 0; mi < 4; ++mi)
        #pragma unroll
        for (int ni = 0; ni < 4; ++ni)
            accF[mi][ni] = (f32x4){0.f, 0.f, 0.f, 0.f};
    const f32x4 zf = (f32x4){0.f, 0.f, 0.f, 0.f};

    // prologue: A(kt=0) -> bufA[0]; B(s=0) -> bufB[0]; B(s=1) -> bufB[1]; drain.
    #pragma unroll
    for (int i = 0; i < 4; ++i)
        gll16(baseA[i], bufA0 + (wid * 4 + i) * 512);
    #pragma unroll
    for (int i = 0; i < 2; ++i)
        gll16(baseB[i], bufB0 + (wid * 2 + i) * 512);
    #pragma unroll
    for (int i = 0; i < 2; ++i)
        gll16(baseB[i] + (size_t)NPAD * KP, bufB0 + 128 * 64 + (wid * 2 + i) * 512);
    __syncthreads();

    const int xo0 = (l4 * 8) ^ ((lr & 7) << 3);
    const int xo1 = (32 + l4 * 8) ^ ((lr & 7) << 3);
    const int arow = (wr * 64 + lr) * 64;      // af row base (mi adds 16*64)
    const int brow = (wc * 64 + lr) * 64;      // b  row base (ni adds 16*64)

    int kB = 0;                                    // s % 3
    #pragma unroll 1
    for (int kt = 0; kt < 8; ++kt) {
        const short* Ab = bufA0 + (kt & 1) * (256 * 64);

        // hoisted A fragments: valid for all 8 e-steps of this kt
        bf16x8 af0[4], af1[4];
        #pragma unroll
        for (int mi = 0; mi < 4; ++mi) {
            af0[mi] = *(const bf16x8*)(Ab + arow + mi * 1024 + xo0);
            af1[mi] = *(const bf16x8*)(Ab + arow + mi * 1024 + xo1);
        }

        #pragma unroll 1
        for (int e = 0; e < 8; ++e) {
            const short* Bb = bufB0 + kB * (128 * 64);
            const int kB2 = (kB >= 1) ? kB - 1 : kB + 2;   // (s+2) % 3

            // ---- issue prefetches at step top ----
            if (kt < 7 || e < 6) {                 // s+2 <= 63
                const int e2  = (e + 2) & 7;
                const int kt2 = kt + ((e + 2) >> 3);
                const size_t ob = (size_t)e2 * NPAD * KP + (size_t)kt2 * 64;
                #pragma unroll
                for (int i = 0; i < 2; ++i)
                    gll16(baseB[i] + ob, bufB0 + kB2 * (128 * 64) + (wid * 2 + i) * 512);
            }
            if (e == 6 && kt < 7) {
                const size_t oa = (size_t)(kt + 1) * 64;
                #pragma unroll
                for (int i = 0; i < 4; ++i)
                    gll16(baseA[i] + oa,
                          bufA0 + ((kt + 1) & 1) * (256 * 64) + (wid * 4 + i) * 512);
            }

            f32x4 acc[4][4];

            // ---- sub-phase 0: 4 B reads + 16 MFMA (zero-C) ----
            {
                bf16x8 b0[4];
                #pragma unroll
                for (int ni = 0; ni < 4; ++ni)
                    b0[ni] = *(const bf16x8*)(Bb + brow + ni * 1024 + xo0);
                __builtin_amdgcn_s_setprio(1);
                #pragma unroll
                for (int mi = 0; mi < 4; ++mi)
                    #pragma unroll
                    for (int ni = 0; ni < 4; ++ni)
                        acc[mi][ni] = __builtin_amdgcn_mfma_f32_16x16x32_bf16(
                            af0[mi], b0[ni], zf, 0, 0, 0);
                __builtin_amdgcn_s_setprio(0);
            }
            // ---- sub-phase 1: 4 B reads + 16 MFMA ----
            {
                bf16x8 b1[4];
                #pragma unroll
                for (int ni = 0; ni < 4; ++ni)
                    b1[ni] = *(const bf16x8*)(Bb + brow + ni * 1024 + xo1);
                __builtin_amdgcn_s_setprio(1);
                #pragma unroll
                for (int mi = 0; mi < 4; ++mi)
                    #pragma unroll
                    for (int ni = 0; ni < 4; ++ni)
                        acc[mi][ni] = __builtin_amdgcn_mfma_f32_16x16x32_bf16(
                            af1[mi], b1[ni], acc[mi][ni], 0, 0, 0);
                __builtin_amdgcn_s_setprio(0);
            }

            // ---- per-step mix: accF += w_e[row] * acc (VALU pipe) ----
            {
                f32x4 wv[4];
                #pragma unroll
                for (int mi = 0; mi < 4; ++mi)
                    wv[mi] = *(const f32x4*)&wlsT[e][wr * 64 + mi * 16 + l4 * 4];
                #pragma unroll
                for (int mi = 0; mi < 4; ++mi)
                    #pragma unroll
                    for (int ni = 0; ni < 4; ++ni)
                        #pragma unroll
                        for (int j = 0; j < 4; ++j)
                            accF[mi][ni][j] += wv[mi][j] * acc[mi][ni][j];
            }

            // ---- end-of-step: FIFO-counted wait, single publish barrier ----
            if (kt == 7 && e >= 6)      asm volatile("s_waitcnt vmcnt(0)" ::: "memory");
            else if (e == 6)            asm volatile("s_waitcnt vmcnt(6)" ::: "memory");
            else                        asm volatile("s_waitcnt vmcnt(2)" ::: "memory");
            asm volatile("s_barrier" ::: "memory");

            kB = (kB == 2) ? 0 : kB + 1;
        }
    }

    // epilogue: rank-1 bias term  accF += sum_e w_e[row] * bias_e[col]
    {
        float bv[4][NEXP];
        #pragma unroll
        for (int ni = 0; ni < 4; ++ni) {
            int ng = n0 + wc * 64 + ni * 16 + lr;
            #pragma unroll
            for (int e = 0; e < NEXP; ++e)
                bv[ni][e] = (ng < NREAL) ? bias[(size_t)e * NREAL + ng] : 0.f;
        }
        #pragma unroll
        for (int mi = 0; mi < 4; ++mi) {
            f32x4 wve[NEXP];
            #pragma unroll
            for (int e = 0; e < NEXP; ++e)
                wve[e] = *(const f32x4*)&wlsT[e][wr * 64 + mi * 16 + l4 * 4];
            #pragma unroll
            for (int ni = 0; ni < 4; ++ni)
                #pragma unroll
                for (int j = 0; j < 4; ++j) {
                    float sum = 0.f;
                    #pragma unroll
                    for (int e = 0; e < NEXP; ++e) sum += wve[e][j] * bv[ni][e];
                    accF[mi][ni][j] += sum;
                }
        }
    }

    // store
    #pragma unroll
    for (int mi = 0; mi < 4; ++mi) {
        #pragma unroll
        for (int j = 0; j < 4; ++j) {
            size_t rg = (size_t)(m0 + wr * 64 + mi * 16 + l4 * 4 + j);
            #pragma unroll
            for (int ni = 0; ni < 4; ++ni) {
                int ng = n0 + wc * 64 + ni * 16 + lr;
                float v = accF[mi][ni][j];
                if (MODE == 0) {
                    v = v > 0.f ? v : expf(v) - 1.f;
                    ((short*)Out)[rg * NPAD + ng] = f2bf(v);
                } else {
                    if (ng < NREAL)
                        ((float*)Out)[rg * NREAL + ng] = v * Ynorm[NREAL + ng] + Ynorm[ng];
                }
            }
        }
    }
}

// ---------------------------------------------------------------------------
extern "C" void kernel_launch(void* const* d_in, const int* in_sizes, int n_in,
                              void* d_out, int out_size, void* d_ws, size_t ws_size,
                              hipStream_t stream) {
    const float* x     = (const float*)d_in[0];
    const float* Xnorm = (const float*)d_in[1];
    const float* Ynorm = (const float*)d_in[2];
    const float* G1W   = (const float*)d_in[3];
    const float* G1b   = (const float*)d_in[4];
    const float* G2W   = (const float*)d_in[5];
    const float* G2b   = (const float*)d_in[6];
    const float* G3W   = (const float*)d_in[7];
    const float* G3b   = (const float*)d_in[8];
    const float* W1    = (const float*)d_in[9];
    const float* b1    = (const float*)d_in[10];
    const float* W2    = (const float*)d_in[11];
    const float* b2    = (const float*)d_in[12];
    const float* W3    = (const float*)d_in[13];
    const float* b3    = (const float*)d_in[14];
    const int*   gidx  = (const int*)d_in[15];

    // workspace layout (m2 aliases xnbf: xnbf is fully consumed by layer 1)
    char* ws = (char*)d_ws;
    size_t off = 0;
    short* xnbf = (short*)(ws + off); off += (size_t)BATCH * KP * 2;        // 16.8 MB
    short* m1   = (short*)(ws + off); off += (size_t)BATCH * DH * 2;        // 16.8 MB
    short* Wt1  = (short*)(ws + off); off += (size_t)NEXP * DH  * KP * 2;   // 4.2 MB
    short* Wt2  = (short*)(ws + off); off += (size_t)NEXP * DH  * KP * 2;   // 4.2 MB
    short* Wt3  = (short*)(ws + off); off += (size_t)NEXP * 384 * KP * 2;   // 3.1 MB
    float* wg   = (float*)(ws + off); off += (size_t)BATCH * NEXP * 4;      // 0.5 MB
    short* m2   = xnbf;
    if (off > ws_size) return;

    // 1. normalize x -> bf16 (pitch 512, zero-padded)
    prep_xn_kernel<<<BATCH * 64 / 256, 256, 0, stream>>>(x, Xnorm, xnbf);

    // 2. transpose all weights to [E][NPAD][KP] bf16 in ONE launch
    transpose_all_kernel<<<5632, 256, 0, stream>>>(W1, Wt1, W2, Wt2, W3, Wt3);

    // 3. gating -> w[B][8]
    gating_kernel<<<256, 256, 0, stream>>>(x, Xnorm, G1W, G1b, G2W, G2b, G3W, G3b, gidx, wg);

    // 4. expert layers (BM=256, BN=128)
    expert_v8_kernel<DH, DH, 0>
        <<<(BATCH / 256) * (DH / 128), 512, 0, stream>>>(xnbf, Wt1, wg, b1, Ynorm, m1);
    expert_v8_kernel<DH, DH, 0>
        <<<(BATCH / 256) * (DH / 128), 512, 0, stream>>>(m1, Wt2, wg, b2, Ynorm, m2);
    expert_v8_kernel<384, DOUT, 1>
        <<<(BATCH / 256) * (384 / 128), 512, 0, stream>>>(m2, Wt3, wg, b3, Ynorm, (void*)d_out);
}